// Round 1
// baseline (817.679 us; speedup 1.0000x reference)
//
#include <hip/hip_runtime.h>

#define H 512
#define MTILE 64
#define NBLK 8192
#define HPAD 520
#define STEPC (2.4f / 63.0f)

typedef _Float16 half8 __attribute__((ext_vector_type(8)));
typedef _Float16 half4_t __attribute__((ext_vector_type(4)));
typedef _Float16 half2_t __attribute__((ext_vector_type(2)));
typedef float floatx4 __attribute__((ext_vector_type(4)));

// fast silu: native exp + native rcp (v_exp_f32 / v_rcp_f32), no fp32 div seq.
// rcp rel-err ~1e-7 -- negligible vs fp16-h rounding (absmax budget 2.9e-3).
__device__ inline float silu_f(float x) {
    return __fdividef(x, 1.0f + __expf(-x));
}

// ---- prep 1: lat_part[b][j] = b0[j] + sum_d lat[b][d] * W0[d][j] ----
__global__ void prep_latw(const float* __restrict__ lat, const float* __restrict__ W0,
                          const float* __restrict__ b0, float* __restrict__ latw) {
    __shared__ float sl[H];
    const int b = blockIdx.x;
    const int j = threadIdx.x;
    sl[j] = lat[b * H + j];
    __syncthreads();
    float acc = b0[j];
#pragma unroll 8
    for (int d = 0; d < H; ++d) acc += sl[d] * W0[d * H + j];
    latw[b * H + j] = acc;
}

// ---- prep 2: W1/W2 -> fp16, fragment-major for direct L2->reg loads ----
// kc=k>>5, q=(k>>3)&3, k0=k&7;  idx = (((l*16+kc)*4+q)*512 + n)*8 + k0
// (unchanged: the 16x16x32 A-role and B-role fragment layouts are symmetric,
//  so the same image serves the W operand in the swapped mfma call)
__global__ void prep_w16(const float* __restrict__ W1, const float* __restrict__ W2,
                         _Float16* __restrict__ ws) {
    const int id = blockIdx.x * 512 + threadIdx.x;   // 0 .. 524287
    const int l = id >> 18;
    const int rem = id & 0x3FFFF;                    // k*512 + n
    const int k = rem >> 9, n = rem & 511;
    const float w = (l == 0 ? W1 : W2)[rem];
    const int kc = k >> 5, q = (k >> 3) & 3, k0 = k & 7;
    ws[((size_t)((l * 16 + kc) * 4 + q) * 512 + n) * 8 + k0] = (_Float16)w;
}

// ---- main fused kernel: barrier-free K-loop, B from L2, 2 blocks/CU ----
// R1 change: SWAPPED-OPERAND MFMA -- mfma(W_frag, h_frag) computes C with
// col=lane&15 -> m-row, reg r -> n = nt*128 + wave*16 + q*4 + r.
// Each lane then owns 4 CONSECUTIVE n at a fixed row:
//   * writeback: 16x ds_write_b64 (packed half4) instead of 64x ds_write_b16
//   * final:     2 shfl_xor (over q: 16,32) instead of 4 (over t), i.e.
//                8 swizzles/thread instead of 64; b2/W3 as float4 loads
//   * layer 0:   2 cols x 32 rows per thread -> packed b32 stores
__global__ __launch_bounds__(512, 4) void mesh_main(
    const float* __restrict__ W0, const float* __restrict__ b1,
    const float* __restrict__ b2, const float* __restrict__ W3,
    const float* __restrict__ b3, const float* __restrict__ latw,
    const _Float16* __restrict__ wsB, float* __restrict__ out) {

    __shared__ _Float16 hbuf[MTILE][HPAD];        // 66.5 KB
    __shared__ float partials[8][MTILE];          // 2 KB  -> 68.6 KB total

    const int tid = threadIdx.x;
    const int wave = tid >> 6, lane = tid & 63;
    const int q = lane >> 4, t = lane & 15;
    const int bi = blockIdx.x;
    const int b = bi >> 12;
    const int p0 = (bi & 4095) << 6;              // 64 rows per block (fixed x,y)
    const float c0 = -1.2f + (float)(p0 >> 12) * STEPC;
    const float c1 = -1.2f + (float)((p0 >> 6) & 63) * STEPC;

    // ---- layer 0: h0 = silu(lat_part + coords@W0c + b0), fp32 VALU ----
    // 2 adjacent cols x 32 rows per thread: packed 4B stores, conflict-free
    {
        const int cp = tid & 255, mh = tid >> 8;
        const int j0 = cp * 2;
        const float w2c0 = W0[(H + 2) * H + j0];
        const float w2c1 = W0[(H + 2) * H + j0 + 1];
        const float lw0 = latw[b * H + j0]
                        + c0 * W0[(H + 0) * H + j0]
                        + c1 * W0[(H + 1) * H + j0];
        const float lw1 = latw[b * H + j0 + 1]
                        + c0 * W0[(H + 0) * H + j0 + 1]
                        + c1 * W0[(H + 1) * H + j0 + 1];
#pragma unroll 4
        for (int mm = 0; mm < 32; ++mm) {
            const int m = mh * 32 + mm;
            const float c2v = -1.2f + (float)m * STEPC;
            half2_t hv;
            hv[0] = (_Float16)silu_f(lw0 + c2v * w2c0);
            hv[1] = (_Float16)silu_f(lw1 + c2v * w2c1);
            *(half2_t*)&hbuf[m][j0] = hv;
        }
    }

    // per-lane base into the B image (quad + lane column part)
    const _Float16* wsl = wsB + ((size_t)q * 512 + wave * 16 + t) * 8;

    floatx4 acc[4][4];     // [mf][nt] — all indices compile-time constant

    auto zero_acc = [&]() {
#pragma unroll
        for (int mf = 0; mf < 4; ++mf)
#pragma unroll
            for (int nt = 0; nt < 4; ++nt) {
                acc[mf][nt][0] = 0.f; acc[mf][nt][1] = 0.f;
                acc[mf][nt][2] = 0.f; acc[mf][nt][3] = 0.f;
            }
    };

    auto loadB = [&](int l, int kc, half8 (&bf)[4]) {
        const _Float16* p = wsl + (size_t)(l * 16 + kc) * 16384;
#pragma unroll
        for (int nt = 0; nt < 4; ++nt)
            bf[nt] = *(const half8*)(p + nt * 1024);   // nt*128 cols * 8
    };

    auto compute = [&](int kc, half8 (&bf)[4]) {
        half8 a[4];
#pragma unroll
        for (int mf = 0; mf < 4; ++mf)
            a[mf] = *(const half8*)&hbuf[mf * 16 + t][kc * 32 + q * 8];
#pragma unroll
        for (int nt = 0; nt < 4; ++nt)
#pragma unroll
            for (int mf = 0; mf < 4; ++mf)
                acc[mf][nt] = __builtin_amdgcn_mfma_f32_16x16x32_f16(bf[nt], a[mf], acc[mf][nt], 0, 0, 0);
    };

    auto run_gemm = [&](int l) {
        half8 B0[4], B1[4];
        loadB(l, 0, B0);
#pragma unroll 1
        for (int kc = 0; kc < 16; kc += 2) {
            loadB(l, kc + 1, B1);
            compute(kc, B0);
            loadB(l, (kc + 2) & 15, B0);    // wraps to 0 on last iter: harmless
            compute(kc + 1, B1);
        }
    };

    // ---- GEMM 1 ----
    zero_acc();
    __syncthreads();             // h0 ready
    run_gemm(0);
    __syncthreads();             // all waves done reading h0
    // writeback h1 = silu(acc + b1): packed half4 (b64) stores, float4 bias
    {
        floatx4 b1v[4];
#pragma unroll
        for (int nt = 0; nt < 4; ++nt)
            b1v[nt] = *(const floatx4*)&b1[nt * 128 + wave * 16 + q * 4];
#pragma unroll
        for (int mf = 0; mf < 4; ++mf)
#pragma unroll
            for (int nt = 0; nt < 4; ++nt) {
                half4_t hv;
#pragma unroll
                for (int r = 0; r < 4; ++r)
                    hv[r] = (_Float16)silu_f(acc[mf][nt][r] + b1v[nt][r]);
                *(half4_t*)&hbuf[mf * 16 + t][nt * 128 + wave * 16 + q * 4] = hv;
            }
    }

    // ---- GEMM 2 ----
    zero_acc();
    __syncthreads();             // h1 ready
    run_gemm(1);

    // ---- final layer: out = silu(acc + b2) @ W3 + b3, fp32 VALU ----
    // per-lane n are consecutive -> float4 b2/W3 loads, reduce over q only
    {
        floatx4 b2v[4], w3v[4];
#pragma unroll
        for (int nt = 0; nt < 4; ++nt) {
            b2v[nt] = *(const floatx4*)&b2[nt * 128 + wave * 16 + q * 4];
            w3v[nt] = *(const floatx4*)&W3[nt * 128 + wave * 16 + q * 4];
        }
#pragma unroll
        for (int mf = 0; mf < 4; ++mf) {
            float sum = 0.f;
#pragma unroll
            for (int nt = 0; nt < 4; ++nt)
#pragma unroll
                for (int r = 0; r < 4; ++r)
                    sum += silu_f(acc[mf][nt][r] + b2v[nt][r]) * w3v[nt][r];
            sum += __shfl_xor(sum, 16);
            sum += __shfl_xor(sum, 32);
            if (lane < 16) partials[wave][mf * 16 + t] = sum;
        }
    }
    __syncthreads();
    if (tid < MTILE) {
        float o = b3[0];
#pragma unroll
        for (int w = 0; w < 8; ++w) o += partials[w][tid];
        out[(size_t)bi * MTILE + tid] = o;
    }
}

extern "C" void kernel_launch(void* const* d_in, const int* in_sizes, int n_in,
                              void* d_out, int out_size, void* d_ws, size_t ws_size,
                              hipStream_t stream) {
    const float* lat = (const float*)d_in[0];
    const float* W0  = (const float*)d_in[1];
    const float* b0  = (const float*)d_in[2];
    const float* W1  = (const float*)d_in[3];
    const float* b1  = (const float*)d_in[4];
    const float* W2  = (const float*)d_in[5];
    const float* b2  = (const float*)d_in[6];
    const float* W3  = (const float*)d_in[7];
    const float* b3  = (const float*)d_in[8];
    float* out = (float*)d_out;

    float* latw = (float*)d_ws;                               // 4 KB
    _Float16* wsB = (_Float16*)((char*)d_ws + 4096);          // 1 MB

    prep_latw<<<2, 512, 0, stream>>>(lat, W0, b0, latw);
    prep_w16<<<1024, 512, 0, stream>>>(W1, W2, wsB);
    mesh_main<<<NBLK, 512, 0, stream>>>(W0, b1, b2, W3, b3, latw, wsB, out);
}

// Round 2
// 811.677 us; speedup vs baseline: 1.0074x; 1.0074x over previous
//
#include <hip/hip_runtime.h>

#define H 512
#define MTILE 64
#define NBLK 8192
#define STEPC (2.4f / 63.0f)

typedef _Float16 half8 __attribute__((ext_vector_type(8)));
typedef _Float16 half4_t __attribute__((ext_vector_type(4)));
typedef float floatx4 __attribute__((ext_vector_type(4)));
typedef float floatx2 __attribute__((ext_vector_type(2)));

// fast silu: native exp + native rcp. rel-err ~1e-7, negligible vs fp16 rounding.
__device__ inline float silu_f(float x) {
    return __fdividef(x, 1.0f + __expf(-x));
}

// ---- prep 1: lat_part[b][j] = b0[j] + sum_d lat[b][d] * W0[d][j] ----
__global__ void prep_latw(const float* __restrict__ lat, const float* __restrict__ W0,
                          const float* __restrict__ b0, float* __restrict__ latw) {
    __shared__ float sl[H];
    const int b = blockIdx.x;
    const int j = threadIdx.x;
    sl[j] = lat[b * H + j];
    __syncthreads();
    float acc = b0[j];
#pragma unroll 8
    for (int d = 0; d < H; ++d) acc += sl[d] * W0[d * H + j];
    latw[b * H + j] = acc;
}

// ---- prep 2: W1/W2 -> fp16, fragment-major for direct L2->reg loads ----
// kc=k>>5, q=(k>>3)&3, k0=k&7;  idx = (((l*16+kc)*4+q)*512 + n)*8 + k0
__global__ void prep_w16(const float* __restrict__ W1, const float* __restrict__ W2,
                         _Float16* __restrict__ ws) {
    const int id = blockIdx.x * 512 + threadIdx.x;   // 0 .. 524287
    const int l = id >> 18;
    const int rem = id & 0x3FFFF;                    // k*512 + n
    const int k = rem >> 9, n = rem & 511;
    const float w = (l == 0 ? W1 : W2)[rem];
    const int kc = k >> 5, q = (k >> 3) & 3, k0 = k & 7;
    ws[((size_t)((l * 16 + kc) * 4 + q) * 512 + n) * 8 + k0] = (_Float16)w;
}

// ---- main fused kernel ----
// R2 change: FRAGMENT-MAJOR LDS for h (same layout family as wsB).
//   h element [row][col] lives at hbuf2[((col>>3)*64 + row)*8 + (col&7)].
//   * K-loop A-read (lane q,t; tile kc,mf): contiguous b128 at
//     q*512 + t*8 + kc*2048 + mf*128 halves -> 4x256B contiguous runs per
//     wave: conflict-free, and kc/mf fold into ds_read offset immediates.
//   * GEMM1 writeback: lane's 4 consecutive n = one region, k0=(q&1)*4+r ->
//     single b64 write, 32 lanes per contiguous 256B run: conflict-free.
//   * layer 0: lw[j] precomputed to LDS (phase A), then per-row phase B
//     packs half8 and writes 8x b128 per lane, each a contiguous 1KB
//     wave-write: conflict-free (was 32x scattered b32).
// VGPR discipline: stays at 64 VGPR + 64 AGPR = 128 total (4 waves/SIMD,
// 2 blocks/CU with 70KB LDS). No extra prefetch buffers (would cross cliff).
__global__ __launch_bounds__(512, 4) void mesh_main(
    const float* __restrict__ W0, const float* __restrict__ b1,
    const float* __restrict__ b2, const float* __restrict__ W3,
    const float* __restrict__ b3, const float* __restrict__ latw,
    const _Float16* __restrict__ wsB, float* __restrict__ out) {

    __shared__ _Float16 hbuf2[4096 * 8];          // 64 KB, fragment-major
    __shared__ float lwbuf[2 * H];                // 4 KB: (lw, w2c) pairs
    __shared__ float partials[8][MTILE];          // 2 KB  -> 70 KB total

    const int tid = threadIdx.x;
    const int wave = tid >> 6, lane = tid & 63;
    const int q = lane >> 4, t = lane & 15;
    const int bi = blockIdx.x;
    const int b = bi >> 12;
    const int p0 = (bi & 4095) << 6;              // 64 rows per block (fixed x,y)
    const float c0 = -1.2f + (float)(p0 >> 12) * STEPC;
    const float c1 = -1.2f + (float)((p0 >> 6) & 63) * STEPC;

    // ---- layer 0, phase A: lw[j] = latw + c0*W0x + c1*W0y; w2c[j] = W0z ----
    {
        const int j = tid;
        const float lwv = latw[b * H + j]
                        + c0 * W0[(H + 0) * H + j]
                        + c1 * W0[(H + 1) * H + j];
        floatx2 v;
        v[0] = lwv;
        v[1] = W0[(H + 2) * H + j];
        *(floatx2*)&lwbuf[2 * j] = v;             // contiguous b64: conflict-free
    }
    __syncthreads();

    // ---- layer 0, phase B: row m = lane; regions g = wave*8+s (8 cols each) ----
    {
        const float c2v = -1.2f + (float)lane * STEPC;
#pragma unroll
        for (int s = 0; s < 8; ++s) {
            const int g = wave * 8 + s;
            const floatx4* lp = (const floatx4*)&lwbuf[g * 16];  // broadcast reads
            half8 hv;
#pragma unroll
            for (int i = 0; i < 4; ++i) {
                const floatx4 pv = lp[i];          // (lw, w2c, lw, w2c)
                hv[2 * i + 0] = (_Float16)silu_f(pv[0] + c2v * pv[1]);
                hv[2 * i + 1] = (_Float16)silu_f(pv[2] + c2v * pv[3]);
            }
            *(half8*)&hbuf2[(g * 64 + lane) * 8] = hv;  // 1KB contiguous per wave
        }
    }

    // per-lane bases
    const _Float16* wsl = wsB + ((size_t)q * 512 + wave * 16 + t) * 8;
    const _Float16* hb = hbuf2 + q * 512 + t * 8;

    floatx4 acc[4][4];     // [mf][nt] — all indices compile-time constant

    auto zero_acc = [&]() {
#pragma unroll
        for (int mf = 0; mf < 4; ++mf)
#pragma unroll
            for (int nt = 0; nt < 4; ++nt) {
                acc[mf][nt][0] = 0.f; acc[mf][nt][1] = 0.f;
                acc[mf][nt][2] = 0.f; acc[mf][nt][3] = 0.f;
            }
    };

    auto loadB = [&](int l, int kc, half8 (&bf)[4]) {
        const _Float16* p = wsl + (size_t)(l * 16 + kc) * 16384;
#pragma unroll
        for (int nt = 0; nt < 4; ++nt)
            bf[nt] = *(const half8*)(p + nt * 1024);   // nt*128 cols * 8
    };

    auto compute = [&](int kc, half8 (&bf)[4]) {
        half8 a[4];
        const _Float16* hp = hb + kc * 2048;
#pragma unroll
        for (int mf = 0; mf < 4; ++mf)
            a[mf] = *(const half8*)(hp + mf * 128);    // conflict-free b128
#pragma unroll
        for (int nt = 0; nt < 4; ++nt)
#pragma unroll
            for (int mf = 0; mf < 4; ++mf)
                acc[mf][nt] = __builtin_amdgcn_mfma_f32_16x16x32_f16(bf[nt], a[mf], acc[mf][nt], 0, 0, 0);
    };

    auto run_gemm = [&](int l) {
        half8 B0[4], B1[4];
        loadB(l, 0, B0);
#pragma unroll 1
        for (int kc = 0; kc < 16; kc += 2) {
            loadB(l, kc + 1, B1);
            compute(kc, B0);
            loadB(l, (kc + 2) & 15, B0);    // wraps to 0 on last iter: harmless
            compute(kc + 1, B1);
        }
    };

    // ---- GEMM 1 ----
    zero_acc();
    __syncthreads();             // h0 ready
    run_gemm(0);
    __syncthreads();             // all waves done reading h0
    // writeback h1 = silu(acc + b1): lane owns n = nt*128+wave*16+q*4 .. +3
    // target region = n>>3 = nt*16 + R0, k0 = (q&1)*4 + r
    {
        const int R0 = (wave >> 1) * 4 + (wave & 1) * 2 + (q >> 1);
        _Float16* wb = hbuf2 + R0 * 512 + t * 8 + (q & 1) * 4;
        floatx4 b1v[4];
#pragma unroll
        for (int nt = 0; nt < 4; ++nt)
            b1v[nt] = *(const floatx4*)&b1[nt * 128 + wave * 16 + q * 4];
#pragma unroll
        for (int mf = 0; mf < 4; ++mf)
#pragma unroll
            for (int nt = 0; nt < 4; ++nt) {
                half4_t hv;
#pragma unroll
                for (int r = 0; r < 4; ++r)
                    hv[r] = (_Float16)silu_f(acc[mf][nt][r] + b1v[nt][r]);
                *(half4_t*)(wb + nt * 8192 + mf * 128) = hv;  // conflict-free b64
            }
    }

    // ---- GEMM 2 ----
    zero_acc();
    __syncthreads();             // h1 ready
    run_gemm(1);

    // ---- final layer: out = silu(acc + b2) @ W3 + b3, fp32 VALU ----
    {
        floatx4 b2v[4], w3v[4];
#pragma unroll
        for (int nt = 0; nt < 4; ++nt) {
            b2v[nt] = *(const floatx4*)&b2[nt * 128 + wave * 16 + q * 4];
            w3v[nt] = *(const floatx4*)&W3[nt * 128 + wave * 16 + q * 4];
        }
#pragma unroll
        for (int mf = 0; mf < 4; ++mf) {
            float sum = 0.f;
#pragma unroll
            for (int nt = 0; nt < 4; ++nt)
#pragma unroll
                for (int r = 0; r < 4; ++r)
                    sum += silu_f(acc[mf][nt][r] + b2v[nt][r]) * w3v[nt][r];
            sum += __shfl_xor(sum, 16);
            sum += __shfl_xor(sum, 32);
            if (lane < 16) partials[wave][mf * 16 + t] = sum;
        }
    }
    __syncthreads();
    if (tid < MTILE) {
        float o = b3[0];
#pragma unroll
        for (int w = 0; w < 8; ++w) o += partials[w][tid];
        out[(size_t)bi * MTILE + tid] = o;
    }
}

extern "C" void kernel_launch(void* const* d_in, const int* in_sizes, int n_in,
                              void* d_out, int out_size, void* d_ws, size_t ws_size,
                              hipStream_t stream) {
    const float* lat = (const float*)d_in[0];
    const float* W0  = (const float*)d_in[1];
    const float* b0  = (const float*)d_in[2];
    const float* W1  = (const float*)d_in[3];
    const float* b1  = (const float*)d_in[4];
    const float* W2  = (const float*)d_in[5];
    const float* b2  = (const float*)d_in[6];
    const float* W3  = (const float*)d_in[7];
    const float* b3  = (const float*)d_in[8];
    float* out = (float*)d_out;

    float* latw = (float*)d_ws;                               // 4 KB
    _Float16* wsB = (_Float16*)((char*)d_ws + 4096);          // 1 MB

    prep_latw<<<2, 512, 0, stream>>>(lat, W0, b0, latw);
    prep_w16<<<1024, 512, 0, stream>>>(W1, W2, wsB);
    mesh_main<<<NBLK, 512, 0, stream>>>(W0, b1, b2, W3, b3, latw, wsB, out);
}